// Round 1
// baseline (169.625 us; speedup 1.0000x reference)
//
#include <hip/hip_runtime.h>

typedef unsigned short ushort_t;
typedef __bf16 bf16x8 __attribute__((ext_vector_type(8)));
typedef float f32x4 __attribute__((ext_vector_type(4)));

#define DEVI __device__ __forceinline__

constexpr int BSZ = 4;     // batch
constexpr int MDIM = 190;  // axial dim
constexpr int TDIM = 512;  // seq
constexpr int CDIM = 64;   // channels
constexpr int NHEAD = 4;
// D = 16

DEVI ushort_t f2bf(float f) {
    union { float f; unsigned int u; } v; v.f = f;
    unsigned int u = v.u;
    u += 0x7FFFu + ((u >> 16) & 1u);   // round-to-nearest-even
    return (ushort_t)(u >> 16);
}

// ---------------------------------------------------------------- K1: xsum
__global__ __launch_bounds__(256) void k_xsum(const float* __restrict__ x,
                                              float* __restrict__ xsum) {
    int idx = blockIdx.x * 256 + threadIdx.x;   // 131072 = 4*512*64
    int b = idx >> 15;
    size_t base = (size_t)b * (MDIM * TDIM * CDIM) + (idx & 32767);
    const float* p = x + base;
    const size_t stride = (size_t)TDIM * CDIM;  // 32768
    float s[8];
#pragma unroll
    for (int u = 0; u < 8; ++u) s[u] = 0.f;
    int m = 0;
    for (; m + 8 <= MDIM; m += 8) {
#pragma unroll
        for (int u = 0; u < 8; ++u) s[u] += p[(size_t)u * stride];
        p += 8 * stride;
    }
#pragma unroll
    for (int u = 0; u < 6; ++u) s[u] += p[(size_t)u * stride];  // 190 = 184+6
    float t0 = (s[0] + s[1]) + (s[2] + s[3]);
    float t1 = (s[4] + s[5]) + (s[6] + s[7]);
    xsum[idx] = t0 + t1;
}

// ---------------------------------------------------------------- K2: weights (qt/kt + softmax)
__global__ __launch_bounds__(256) void k_weights(const float* __restrict__ xsum,
                                                 const float* __restrict__ Wq,
                                                 const float* __restrict__ bq,
                                                 const float* __restrict__ Wk,
                                                 const float* __restrict__ bk,
                                                 ushort_t* __restrict__ wbf,
                                                 float* __restrict__ a_out) {
    __shared__ __align__(16) float kt[512][20];
    __shared__ __align__(16) float qt[32][20];
    __shared__ __align__(16) float xs[64][68];
    __shared__ __align__(16) float wcol[64][16];
    __shared__ float kbias[16], qbias[16];

    int tid = threadIdx.x;
    int bid = blockIdx.x;        // 256 blocks
    int tcn = bid & 15;          // t-chunk (32 rows)
    int n = (bid >> 4) & 3;
    int b = bid >> 6;
    int t0 = tcn * 32;

    for (int j = tid; j < 1024; j += 256) {
        int c = j >> 4, d = j & 15;
        wcol[c][d] = Wk[c * 64 + n * 16 + d];
    }
    if (tid < 16) kbias[tid] = 190.0f * bk[n * 16 + tid];
    if (tid >= 16 && tid < 32) qbias[tid - 16] = 190.0f * bq[n * 16 + tid - 16];
    __syncthreads();

    // kt[512][16] over 8 chunks of 64 rows
    for (int ch = 0; ch < 8; ++ch) {
        for (int j = tid; j < 4096; j += 256) {
            int t = j >> 6, c = j & 63;
            xs[t][c] = xsum[((size_t)(b * 512) + (ch * 64 + t)) * 64 + c];
        }
        __syncthreads();
#pragma unroll
        for (int o = 0; o < 4; ++o) {
            int oi = o * 256 + tid;
            int t = oi >> 4, d = oi & 15;
            float s = 0.f;
#pragma unroll
            for (int c = 0; c < 64; ++c) s += xs[t][c] * wcol[c][d];
            kt[ch * 64 + t][d] = s + kbias[d];
        }
        __syncthreads();
    }

    // qt for this block's 32 rows
    for (int j = tid; j < 1024; j += 256) {
        int c = j >> 4, d = j & 15;
        wcol[c][d] = Wq[c * 64 + n * 16 + d];
    }
    for (int j = tid; j < 2048; j += 256) {
        int t = j >> 6, c = j & 63;
        xs[t][c] = xsum[((size_t)(b * 512) + (t0 + t)) * 64 + c];
    }
    __syncthreads();
#pragma unroll
    for (int o = 0; o < 2; ++o) {
        int oi = o * 256 + tid;
        int t = oi >> 4, d = oi & 15;
        float s = 0.f;
#pragma unroll
        for (int c = 0; c < 64; ++c) s += xs[t][c] * wcol[c][d];
        qt[t][d] = s + qbias[d];
    }
    __syncthreads();

    // fused logits + softmax, one row per wave iteration
    const float scale = 0.01813692f;  // 1/sqrt(16*190)
    int w = tid >> 6, lane = tid & 63;
    for (int rr = 0; rr < 8; ++rr) {
        int r = w * 8 + rr;
        float qreg[16];
#pragma unroll
        for (int d = 0; d < 16; ++d) qreg[d] = qt[r][d];
        float lv[8];
#pragma unroll
        for (int i = 0; i < 8; ++i) {
            int k = lane + 64 * i;
            const float* kr = &kt[k][0];
            float s = 0.f;
#pragma unroll
            for (int d = 0; d < 16; ++d) s += qreg[d] * kr[d];
            lv[i] = s * scale;
        }
        float mx = lv[0];
#pragma unroll
        for (int i = 1; i < 8; ++i) mx = fmaxf(mx, lv[i]);
#pragma unroll
        for (int off = 32; off >= 1; off >>= 1) mx = fmaxf(mx, __shfl_xor(mx, off));
        float se = 0.f;
#pragma unroll
        for (int i = 0; i < 8; ++i) { lv[i] = __expf(lv[i] - mx); se += lv[i]; }
#pragma unroll
        for (int off = 32; off >= 1; off >>= 1) se += __shfl_xor(se, off);
        float inv = 1.0f / se;

        size_t wbase = ((size_t)((b * 4 + n) * 512 + (t0 + r))) * 512;
        size_t abase = ((size_t)(n * 512 + (t0 + r))) * 512;
#pragma unroll
        for (int i = 0; i < 8; ++i) {
            float wv = lv[i] * inv;
            wbf[wbase + lane + 64 * i] = f2bf(wv);
            if (b == 0) a_out[abase + lane + 64 * i] = wv;
        }
    }
}

// ---------------------------------------------------------------- K3: v = x@Wv, store bf16 transposed vt[b][m][c][t]
__global__ __launch_bounds__(256) void k_vproj(const float* __restrict__ x,
                                               const float* __restrict__ Wv,
                                               const float* __restrict__ bv,
                                               ushort_t* __restrict__ vt) {
    __shared__ __align__(16) ushort_t u0[128 * 72];     // Xt [128][72], reused as Vst [64][136]
    __shared__ __align__(16) ushort_t WvT[64 * 72];

    int tid = threadIdx.x;
    int bid = blockIdx.x;                 // 4*190*4 = 3040
    int ttile = bid & 3;
    int m = (bid >> 2) % 190;
    int b = bid / (4 * 190);
    int t0 = ttile * 128;

    size_t xbase = ((size_t)(b * 190 + m) * 512 + t0) * 64;
    // stage x tile -> bf16
#pragma unroll
    for (int rep = 0; rep < 8; ++rep) {
        int j = rep * 256 + tid;          // 2048 float4 units
        int t = j >> 4, c4 = (j & 15) * 4;
        float4 v = *(const float4*)(x + xbase + (size_t)t * 64 + c4);
        ushort4 h;
        h.x = f2bf(v.x); h.y = f2bf(v.y); h.z = f2bf(v.z); h.w = f2bf(v.w);
        *(ushort4*)&u0[t * 72 + c4] = h;
    }
    // Wv transposed
#pragma unroll
    for (int rep = 0; rep < 16; ++rep) {
        int j = rep * 256 + tid;
        int ci = j >> 6, co = j & 63;
        WvT[co * 72 + ci] = f2bf(Wv[j]);
    }
    __syncthreads();

    int w = tid >> 6, lane = tid & 63;
    int la = lane & 15, lb = lane >> 4;
    f32x4 zz = {0.f, 0.f, 0.f, 0.f};
    f32x4 acc[2][4];
#pragma unroll
    for (int q = 0; q < 2; ++q)
#pragma unroll
        for (int cf = 0; cf < 4; ++cf) acc[q][cf] = zz;

#pragma unroll
    for (int ks = 0; ks < 2; ++ks) {
        bf16x8 a0 = *(const bf16x8*)&u0[(32 * w + la) * 72 + ks * 32 + lb * 8];
        bf16x8 a1 = *(const bf16x8*)&u0[(32 * w + 16 + la) * 72 + ks * 32 + lb * 8];
#pragma unroll
        for (int cf = 0; cf < 4; ++cf) {
            bf16x8 bb = *(const bf16x8*)&WvT[(16 * cf + la) * 72 + ks * 32 + lb * 8];
            acc[0][cf] = __builtin_amdgcn_mfma_f32_16x16x32_bf16(a0, bb, acc[0][cf], 0, 0, 0);
            acc[1][cf] = __builtin_amdgcn_mfma_f32_16x16x32_bf16(a1, bb, acc[1][cf], 0, 0, 0);
        }
    }
    __syncthreads();   // Xt region now reusable as Vst

    float bvv[4];
#pragma unroll
    for (int cf = 0; cf < 4; ++cf) bvv[cf] = bv[16 * cf + la];

#pragma unroll
    for (int q = 0; q < 2; ++q)
#pragma unroll
        for (int cf = 0; cf < 4; ++cf) {
            int t = 32 * w + 16 * q + lb * 4;
            int c = 16 * cf + la;
            ushort4 h;
            h.x = f2bf(acc[q][cf][0] + bvv[cf]);
            h.y = f2bf(acc[q][cf][1] + bvv[cf]);
            h.z = f2bf(acc[q][cf][2] + bvv[cf]);
            h.w = f2bf(acc[q][cf][3] + bvv[cf]);
            *(ushort4*)&u0[c * 136 + t] = h;   // Vst[c][t]
        }
    __syncthreads();

    size_t vbase = ((size_t)(b * 190 + m) * 64) * 512 + t0;
#pragma unroll
    for (int rep = 0; rep < 4; ++rep) {
        int j = rep * 256 + tid;           // 1024 16B units
        int c = j >> 4, s = j & 15;
        uint4 vv = *(const uint4*)&u0[c * 136 + s * 8];
        *(uint4*)(vt + vbase + (size_t)c * 512 + s * 8) = vv;
    }
}

// ---------------------------------------------------------------- K4: att = softmax(..)@v, out = att@Wp + bp
__global__ __launch_bounds__(256) void k_att(const ushort_t* __restrict__ wbf,
                                             const ushort_t* __restrict__ vt,
                                             const float* __restrict__ Wp,
                                             const float* __restrict__ bp,
                                             float* __restrict__ out) {
    __shared__ __align__(16) ushort_t ldsA[20480];  // Wtile[4][64][40] @0, VtT[4][64][40] @10240; reused as attS[4][64][72]
    __shared__ __align__(16) ushort_t ldsW[64 * 72];

    int tid = threadIdx.x;
    int bid = blockIdx.x;               // 4*48*8 = 1536
    int ttile = bid & 7;
    int mt = (bid >> 3) % 48;
    int b = bid / (8 * 48);
    int t0 = ttile * 64;

    int w = tid >> 6, lane = tid & 63;
    int la = lane & 15, lb = lane >> 4;
    int m = mt * 4 + w;
    bool mvalid = (m < 190);

    // WpT
#pragma unroll
    for (int rep = 0; rep < 16; ++rep) {
        int j = rep * 256 + tid;
        int ci = j >> 6, co = j & 63;
        ldsW[co * 72 + ci] = f2bf(Wp[j]);
    }

    f32x4 zz = {0.f, 0.f, 0.f, 0.f};
    f32x4 acc[4][4];
#pragma unroll
    for (int n = 0; n < 4; ++n)
#pragma unroll
        for (int q = 0; q < 4; ++q) acc[n][q] = zz;

    int seg = tid & 3, row = tid >> 2;   // 64B-chunk coalesced staging
    for (int kc = 0; kc < 16; ++kc) {
#pragma unroll
        for (int rep = 0; rep < 4; ++rep) {
            int rrw = row + 64 * rep;            // 0..255
            int n = rrw >> 6, i = rrw & 63;
            uint4 v = *(const uint4*)(wbf + ((size_t)((b * 4 + n) * 512 + t0 + i)) * 512 + kc * 32 + seg * 8);
            *(uint4*)(ldsA + (n * 64 + i) * 40 + seg * 8) = v;
            int mm = rrw >> 6, cc = rrw & 63;
            int mg = mt * 4 + mm; if (mg > 189) mg = 189;
            uint4 u = *(const uint4*)(vt + ((size_t)(b * 190 + mg) * 64 + cc) * 512 + kc * 32 + seg * 8);
            *(uint4*)(ldsA + 10240 + (mm * 64 + cc) * 40 + seg * 8) = u;
        }
        __syncthreads();

        bf16x8 bb[4];
#pragma unroll
        for (int n = 0; n < 4; ++n)
            bb[n] = *(const bf16x8*)(ldsA + 10240 + (w * 64 + 16 * n + la) * 40 + lb * 8);
#pragma unroll
        for (int n = 0; n < 4; ++n) {
#pragma unroll
            for (int q = 0; q < 4; ++q) {
                bf16x8 aa = *(const bf16x8*)(ldsA + (n * 64 + 16 * q + la) * 40 + lb * 8);
                acc[n][q] = __builtin_amdgcn_mfma_f32_16x16x32_bf16(aa, bb[n], acc[n][q], 0, 0, 0);
            }
        }
        __syncthreads();
    }

    // stage att (bf16) into reused region: attS[w][t][c'] with 72-elem rows
    ushort_t* attS = ldsA;
#pragma unroll
    for (int n = 0; n < 4; ++n)
#pragma unroll
        for (int q = 0; q < 4; ++q) {
#pragma unroll
            for (int r = 0; r < 4; ++r)
                attS[(w * 64 + 16 * q + lb * 4 + r) * 72 + 16 * n + la] = f2bf(acc[n][q][r]);
        }
    __syncthreads();

    // GEMM2: out = att @ Wp
    f32x4 acc2[4][4];
#pragma unroll
    for (int q = 0; q < 4; ++q)
#pragma unroll
        for (int cf = 0; cf < 4; ++cf) acc2[q][cf] = zz;
#pragma unroll
    for (int ks = 0; ks < 2; ++ks) {
        bf16x8 wb[4];
#pragma unroll
        for (int cf = 0; cf < 4; ++cf)
            wb[cf] = *(const bf16x8*)(ldsW + (16 * cf + la) * 72 + ks * 32 + lb * 8);
#pragma unroll
        for (int q = 0; q < 4; ++q) {
            bf16x8 aa = *(const bf16x8*)(attS + (w * 64 + 16 * q + la) * 72 + ks * 32 + lb * 8);
#pragma unroll
            for (int cf = 0; cf < 4; ++cf)
                acc2[q][cf] = __builtin_amdgcn_mfma_f32_16x16x32_bf16(aa, wb[cf], acc2[q][cf], 0, 0, 0);
        }
    }

    if (mvalid) {
        float bpv[4];
#pragma unroll
        for (int cf = 0; cf < 4; ++cf) bpv[cf] = bp[16 * cf + la];
        size_t obase = ((size_t)(b * 190 + m) * 512 + t0) * 64;
#pragma unroll
        for (int q = 0; q < 4; ++q)
#pragma unroll
            for (int r = 0; r < 4; ++r) {
                int t = 16 * q + lb * 4 + r;
#pragma unroll
                for (int cf = 0; cf < 4; ++cf)
                    out[obase + (size_t)t * 64 + 16 * cf + la] = acc2[q][cf][r] + bpv[cf];
            }
    }
}

// ----------------------------------------------------------------
extern "C" void kernel_launch(void* const* d_in, const int* in_sizes, int n_in,
                              void* d_out, int out_size, void* d_ws, size_t ws_size,
                              hipStream_t stream) {
    const float* x  = (const float*)d_in[0];
    const float* Wq = (const float*)d_in[1];
    const float* bq = (const float*)d_in[2];
    const float* Wk = (const float*)d_in[3];
    const float* bk = (const float*)d_in[4];
    const float* Wv = (const float*)d_in[5];
    const float* bv = (const float*)d_in[6];
    const float* Wp = (const float*)d_in[7];
    const float* bp = (const float*)d_in[8];

    float* out = (float*)d_out;
    float* a_out = out + (size_t)BSZ * MDIM * TDIM * CDIM;   // 24903680

    float* xsum = (float*)d_ws;                                        // 512 KB
    ushort_t* wbf = (ushort_t*)((char*)d_ws + 524288);                 // 8 MB
    ushort_t* vtb = (ushort_t*)((char*)d_ws + 524288 + 8388608);       // 47.5 MB

    k_xsum<<<512, 256, 0, stream>>>(x, xsum);
    k_vproj<<<3040, 256, 0, stream>>>(x, Wv, bv, vtb);
    k_weights<<<256, 256, 0, stream>>>(xsum, Wq, bq, Wk, bk, wbf, a_out);
    k_att<<<1536, 256, 0, stream>>>(wbf, vtb, Wp, bp, out);
}

// Round 2
// 156.370 us; speedup vs baseline: 1.0848x; 1.0848x over previous
//
#include <hip/hip_runtime.h>

typedef unsigned short ushort_t;
typedef __bf16 bf16x8 __attribute__((ext_vector_type(8)));
typedef float f32x4 __attribute__((ext_vector_type(4)));

#define DEVI __device__ __forceinline__

constexpr int BSZ = 4;     // batch
constexpr int MDIM = 190;  // axial dim
constexpr int TDIM = 512;  // seq
constexpr int CDIM = 64;   // channels

DEVI ushort_t f2bf(float f) {
    union { float f; unsigned int u; } v; v.f = f;
    unsigned int u = v.u;
    u += 0x7FFFu + ((u >> 16) & 1u);   // round-to-nearest-even
    return (ushort_t)(u >> 16);
}

DEVI void gload16(ushort_t* ldsBase, const ushort_t* g) {
    __builtin_amdgcn_global_load_lds(
        (const __attribute__((address_space(1))) unsigned int*)g,
        (__attribute__((address_space(3))) unsigned int*)ldsBase, 16, 0, 0);
}

// swizzled LDS read: row-stride 64B tiles, unit s' = lb ^ ((row>>1)&3)
DEVI bf16x8 readSwz(const ushort_t* base, int row, int lb) {
    int s = lb ^ ((row >> 1) & 3);
    return *(const bf16x8*)(base + row * 32 + s * 8);
}

// ---------------------------------------------------------------- K1: xsum (2 m-halves for TLP)
__global__ __launch_bounds__(256) void k_xsum(const float* __restrict__ x,
                                              float* __restrict__ xsum) {
    int bid = blockIdx.x;                       // 1024
    int half = bid >> 9;
    int idx = ((bid & 511) << 8) + threadIdx.x; // 0..131071
    int b = idx >> 15;
    const size_t stride = (size_t)TDIM * CDIM;  // 32768
    size_t base = (size_t)b * (MDIM * TDIM * CDIM) + (size_t)(half * 95) * stride + (idx & 32767);
    const float* p = x + base;
    float s[8];
#pragma unroll
    for (int u = 0; u < 8; ++u) s[u] = 0.f;
    for (int m = 0; m + 8 <= 95; m += 8) {      // 11 iters
#pragma unroll
        for (int u = 0; u < 8; ++u) s[u] += p[(size_t)u * stride];
        p += 8 * stride;
    }
#pragma unroll
    for (int u = 0; u < 7; ++u) s[u] += p[(size_t)u * stride];  // 95 = 88+7
    float t0 = (s[0] + s[1]) + (s[2] + s[3]);
    float t1 = (s[4] + s[5]) + (s[6] + s[7]);
    xsum[(half << 17) + idx] = t0 + t1;
}

// ---------------------------------------------------------------- K2: weights (qt/kt + softmax)
__global__ __launch_bounds__(256) void k_weights(const float* __restrict__ xsum,
                                                 const float* __restrict__ Wq,
                                                 const float* __restrict__ bq,
                                                 const float* __restrict__ Wk,
                                                 const float* __restrict__ bk,
                                                 ushort_t* __restrict__ wbf,
                                                 float* __restrict__ a_out) {
    __shared__ __align__(16) float kt[512][20];
    __shared__ __align__(16) float qt[32][20];
    __shared__ __align__(16) float xs[64][68];
    __shared__ __align__(16) float wcol[64][16];
    __shared__ float kbias[16], qbias[16];

    int tid = threadIdx.x;
    int bid = blockIdx.x;        // 256 blocks
    int tcn = bid & 15;          // t-chunk (32 rows)
    int n = (bid >> 4) & 3;
    int b = bid >> 6;
    int t0 = tcn * 32;

    for (int j = tid; j < 1024; j += 256) {
        int c = j >> 4, d = j & 15;
        wcol[c][d] = Wk[c * 64 + n * 16 + d];
    }
    if (tid < 16) kbias[tid] = 190.0f * bk[n * 16 + tid];
    if (tid >= 16 && tid < 32) qbias[tid - 16] = 190.0f * bq[n * 16 + tid - 16];
    __syncthreads();

    // kt[512][16] over 8 chunks of 64 rows
    for (int ch = 0; ch < 8; ++ch) {
        for (int j = tid; j < 4096; j += 256) {
            int t = j >> 6, c = j & 63;
            size_t ix = ((size_t)(b * 512) + (ch * 64 + t)) * 64 + c;
            xs[t][c] = xsum[ix] + xsum[ix + 131072];
        }
        __syncthreads();
#pragma unroll
        for (int o = 0; o < 4; ++o) {
            int oi = o * 256 + tid;
            int t = oi >> 4, d = oi & 15;
            float s = 0.f;
#pragma unroll
            for (int c = 0; c < 64; ++c) s += xs[t][c] * wcol[c][d];
            kt[ch * 64 + t][d] = s + kbias[d];
        }
        __syncthreads();
    }

    // qt for this block's 32 rows
    for (int j = tid; j < 1024; j += 256) {
        int c = j >> 4, d = j & 15;
        wcol[c][d] = Wq[c * 64 + n * 16 + d];
    }
    for (int j = tid; j < 2048; j += 256) {
        int t = j >> 6, c = j & 63;
        size_t ix = ((size_t)(b * 512) + (t0 + t)) * 64 + c;
        xs[t][c] = xsum[ix] + xsum[ix + 131072];
    }
    __syncthreads();
#pragma unroll
    for (int o = 0; o < 2; ++o) {
        int oi = o * 256 + tid;
        int t = oi >> 4, d = oi & 15;
        float s = 0.f;
#pragma unroll
        for (int c = 0; c < 64; ++c) s += xs[t][c] * wcol[c][d];
        qt[t][d] = s + qbias[d];
    }
    __syncthreads();

    const float scale = 0.01813692f;  // 1/sqrt(16*190)
    int w = tid >> 6, lane = tid & 63;
    for (int rr = 0; rr < 8; ++rr) {
        int r = w * 8 + rr;
        float qreg[16];
#pragma unroll
        for (int d = 0; d < 16; ++d) qreg[d] = qt[r][d];
        float lv[8];
#pragma unroll
        for (int i = 0; i < 8; ++i) {
            int k = lane + 64 * i;
            const float* kr = &kt[k][0];
            float s = 0.f;
#pragma unroll
            for (int d = 0; d < 16; ++d) s += qreg[d] * kr[d];
            lv[i] = s * scale;
        }
        float mx = lv[0];
#pragma unroll
        for (int i = 1; i < 8; ++i) mx = fmaxf(mx, lv[i]);
#pragma unroll
        for (int off = 32; off >= 1; off >>= 1) mx = fmaxf(mx, __shfl_xor(mx, off));
        float se = 0.f;
#pragma unroll
        for (int i = 0; i < 8; ++i) { lv[i] = __expf(lv[i] - mx); se += lv[i]; }
#pragma unroll
        for (int off = 32; off >= 1; off >>= 1) se += __shfl_xor(se, off);
        float inv = 1.0f / se;

        size_t wbase = ((size_t)((b * 4 + n) * 512 + (t0 + r))) * 512;
        size_t abase = ((size_t)(n * 512 + (t0 + r))) * 512;
#pragma unroll
        for (int i = 0; i < 8; ++i) {
            float wv = lv[i] * inv;
            wbf[wbase + lane + 64 * i] = f2bf(wv);
            if (b == 0) a_out[abase + lane + 64 * i] = wv;
        }
    }
}

// ---------------------------------------------------------------- K3: v = x@Wv, store bf16 transposed vt[b][m][c][t]
__global__ __launch_bounds__(256) void k_vproj(const float* __restrict__ x,
                                               const float* __restrict__ Wv,
                                               const float* __restrict__ bv,
                                               ushort_t* __restrict__ vt) {
    __shared__ __align__(16) ushort_t u0[128 * 72];
    __shared__ __align__(16) ushort_t WvT[64 * 72];

    int tid = threadIdx.x;
    int bid = blockIdx.x;                 // 3040
    int ttile = bid & 3;
    int m = (bid >> 2) % 190;
    int b = bid / (4 * 190);
    int t0 = ttile * 128;

    size_t xbase = ((size_t)(b * 190 + m) * 512 + t0) * 64;
#pragma unroll
    for (int rep = 0; rep < 8; ++rep) {
        int j = rep * 256 + tid;
        int t = j >> 4, c4 = (j & 15) * 4;
        float4 v = *(const float4*)(x + xbase + (size_t)t * 64 + c4);
        ushort4 h;
        h.x = f2bf(v.x); h.y = f2bf(v.y); h.z = f2bf(v.z); h.w = f2bf(v.w);
        *(ushort4*)&u0[t * 72 + c4] = h;
    }
#pragma unroll
    for (int rep = 0; rep < 16; ++rep) {
        int j = rep * 256 + tid;
        int ci = j >> 6, co = j & 63;
        WvT[co * 72 + ci] = f2bf(Wv[j]);
    }
    __syncthreads();

    int w = tid >> 6, lane = tid & 63;
    int la = lane & 15, lb = lane >> 4;
    f32x4 zz = {0.f, 0.f, 0.f, 0.f};
    f32x4 acc[2][4];
#pragma unroll
    for (int q = 0; q < 2; ++q)
#pragma unroll
        for (int cf = 0; cf < 4; ++cf) acc[q][cf] = zz;

#pragma unroll
    for (int ks = 0; ks < 2; ++ks) {
        bf16x8 a0 = *(const bf16x8*)&u0[(32 * w + la) * 72 + ks * 32 + lb * 8];
        bf16x8 a1 = *(const bf16x8*)&u0[(32 * w + 16 + la) * 72 + ks * 32 + lb * 8];
#pragma unroll
        for (int cf = 0; cf < 4; ++cf) {
            bf16x8 bb = *(const bf16x8*)&WvT[(16 * cf + la) * 72 + ks * 32 + lb * 8];
            acc[0][cf] = __builtin_amdgcn_mfma_f32_16x16x32_bf16(a0, bb, acc[0][cf], 0, 0, 0);
            acc[1][cf] = __builtin_amdgcn_mfma_f32_16x16x32_bf16(a1, bb, acc[1][cf], 0, 0, 0);
        }
    }
    __syncthreads();

    float bvv[4];
#pragma unroll
    for (int cf = 0; cf < 4; ++cf) bvv[cf] = bv[16 * cf + la];

#pragma unroll
    for (int q = 0; q < 2; ++q)
#pragma unroll
        for (int cf = 0; cf < 4; ++cf) {
            int t = 32 * w + 16 * q + lb * 4;
            int c = 16 * cf + la;
            ushort4 h;
            h.x = f2bf(acc[q][cf][0] + bvv[cf]);
            h.y = f2bf(acc[q][cf][1] + bvv[cf]);
            h.z = f2bf(acc[q][cf][2] + bvv[cf]);
            h.w = f2bf(acc[q][cf][3] + bvv[cf]);
            *(ushort4*)&u0[c * 136 + t] = h;
        }
    __syncthreads();

    size_t vbase = ((size_t)(b * 190 + m) * 64) * 512 + t0;
#pragma unroll
    for (int rep = 0; rep < 4; ++rep) {
        int j = rep * 256 + tid;
        int c = j >> 4, s = j & 15;
        uint4 vv = *(const uint4*)&u0[c * 136 + s * 8];
        *(uint4*)(vt + vbase + (size_t)c * 512 + s * 8) = vv;
    }
}

// ---------------------------------------------------------------- K4: att = W@v then @Wp, global_load_lds + swizzle
__global__ __launch_bounds__(256, 3) void k_att(const ushort_t* __restrict__ wbf,
                                                const ushort_t* __restrict__ vt,
                                                const float* __restrict__ Wp,
                                                const float* __restrict__ bp,
                                                float* __restrict__ out) {
    __shared__ __align__(16) ushort_t lds[24576];   // sW 16KB @0, sV 32KB @8192; epilogue: attS @0 (18432), WpT @18432 (4608)
    ushort_t* sW = lds;
    ushort_t* sV = lds + 8192;

    int tid = threadIdx.x;
    int bid0 = blockIdx.x;                  // 768 = 4b * 24mt * 8tt
    int bid = (bid0 & 7) * 96 + (bid0 >> 3);  // XCD-aware bijective swizzle (768 % 8 == 0)
    int ttile = bid & 7;
    int mt = (bid >> 3) % 24;
    int b = bid / 192;
    int t0 = ttile * 64;

    int w = tid >> 6, lane = tid & 63;
    int la = lane & 15, lb = lane >> 4;

    // ---- precompute staging (source pre-swizzled; LDS dest linear per rule 21)
    unsigned wsrc[4];  ushort_t* wdst[4];
#pragma unroll
    for (int cw = 0; cw < 4; ++cw) {
        int ci = w * 4 + cw;                 // 0..15
        int u = ci * 64 + lane;              // 16B unit
        int r = u >> 2;                      // LDS row (64B)
        int s = (u & 3) ^ ((r >> 1) & 3);    // pre-swizzled source unit
        int n = r >> 6, i = r & 63;
        wsrc[cw] = (unsigned)(((b * 4 + n) * 512 + t0 + i) * 512 + s * 8);
        wdst[cw] = sW + ci * 512;            // ci*1024 bytes
    }
    unsigned vsrc[8];  ushort_t* vdst[8];
#pragma unroll
    for (int cv = 0; cv < 8; ++cv) {
        int cj = w * 8 + cv;                 // 0..31
        int u = cj * 64 + lane;
        int r = u >> 2;                      // 0..511 = mrel*64 + c
        int s = (u & 3) ^ ((r >> 1) & 3);
        int mrel = r >> 6, c = r & 63;
        int mg = mt * 8 + mrel; if (mg > 189) mg = 189;
        vsrc[cv] = (unsigned)(((b * 190 + mg) * 64 + c) * 512 + s * 8);
        vdst[cv] = sV + cj * 512;
    }

    f32x4 zz = {0.f, 0.f, 0.f, 0.f};
    f32x4 acc[2][4][4];
#pragma unroll
    for (int p = 0; p < 2; ++p)
#pragma unroll
        for (int n = 0; n < 4; ++n)
#pragma unroll
            for (int q = 0; q < 4; ++q) acc[p][n][q] = zz;

    // ---- main K loop: 16 chunks of 32 k
    for (int kc = 0; kc < 16; ++kc) {
        int ko = kc * 32;
#pragma unroll
        for (int cw = 0; cw < 4; ++cw) gload16(wdst[cw], wbf + wsrc[cw] + ko);
#pragma unroll
        for (int cv = 0; cv < 8; ++cv) gload16(vdst[cv], vt + vsrc[cv] + ko);
        __syncthreads();   // drains vmcnt(0): staged data visible

#pragma unroll
        for (int n = 0; n < 4; ++n) {
            bf16x8 bb0 = readSwz(sV, (w * 2 + 0) * 64 + 16 * n + la, lb);
            bf16x8 bb1 = readSwz(sV, (w * 2 + 1) * 64 + 16 * n + la, lb);
#pragma unroll
            for (int q = 0; q < 4; ++q) {
                bf16x8 aa = readSwz(sW, n * 64 + 16 * q + la, lb);
                acc[0][n][q] = __builtin_amdgcn_mfma_f32_16x16x32_bf16(aa, bb0, acc[0][n][q], 0, 0, 0);
                acc[1][n][q] = __builtin_amdgcn_mfma_f32_16x16x32_bf16(aa, bb1, acc[1][n][q], 0, 0, 0);
            }
        }
        __syncthreads();   // protect LDS before next stage
    }

    // ---- epilogue: WpT into freed region, att -> LDS (two passes), GEMM2
#pragma unroll
    for (int rep = 0; rep < 16; ++rep) {
        int j = rep * 256 + tid;
        int ci2 = j >> 6, co = j & 63;
        lds[18432 + co * 72 + ci2] = f2bf(Wp[j]);
    }
    float bpv[4];
#pragma unroll
    for (int cf = 0; cf < 4; ++cf) bpv[cf] = bp[16 * cf + la];

    for (int p = 0; p < 2; ++p) {
        int m = mt * 8 + w * 2 + p;
#pragma unroll
        for (int n = 0; n < 4; ++n)
#pragma unroll
            for (int q = 0; q < 4; ++q)
#pragma unroll
                for (int r = 0; r < 4; ++r)
                    lds[(w * 64 + 16 * q + lb * 4 + r) * 72 + 16 * n + la] = f2bf(acc[p][n][q][r]);
        __syncthreads();   // attS + (first pass) WpT visible

        f32x4 acc2[4][4];
#pragma unroll
        for (int q = 0; q < 4; ++q)
#pragma unroll
            for (int cf = 0; cf < 4; ++cf) acc2[q][cf] = zz;
#pragma unroll
        for (int ks = 0; ks < 2; ++ks) {
            bf16x8 wb[4];
#pragma unroll
            for (int cf = 0; cf < 4; ++cf)
                wb[cf] = *(const bf16x8*)(lds + 18432 + (16 * cf + la) * 72 + ks * 32 + lb * 8);
#pragma unroll
            for (int q = 0; q < 4; ++q) {
                bf16x8 aa = *(const bf16x8*)(lds + (w * 64 + 16 * q + la) * 72 + ks * 32 + lb * 8);
#pragma unroll
                for (int cf = 0; cf < 4; ++cf)
                    acc2[q][cf] = __builtin_amdgcn_mfma_f32_16x16x32_bf16(aa, wb[cf], acc2[q][cf], 0, 0, 0);
            }
        }
        if (m < 190) {
            size_t obase = ((size_t)(b * 190 + m) * 512 + t0) * 64;
#pragma unroll
            for (int q = 0; q < 4; ++q)
#pragma unroll
                for (int r = 0; r < 4; ++r) {
                    int t = 16 * q + lb * 4 + r;
#pragma unroll
                    for (int cf = 0; cf < 4; ++cf)
                        out[obase + (size_t)t * 64 + 16 * cf + la] = acc2[q][cf][r] + bpv[cf];
                }
        }
        __syncthreads();   // before pass-1 overwrites attS
    }
}

// ----------------------------------------------------------------
extern "C" void kernel_launch(void* const* d_in, const int* in_sizes, int n_in,
                              void* d_out, int out_size, void* d_ws, size_t ws_size,
                              hipStream_t stream) {
    const float* x  = (const float*)d_in[0];
    const float* Wq = (const float*)d_in[1];
    const float* bq = (const float*)d_in[2];
    const float* Wk = (const float*)d_in[3];
    const float* bk = (const float*)d_in[4];
    const float* Wv = (const float*)d_in[5];
    const float* bv = (const float*)d_in[6];
    const float* Wp = (const float*)d_in[7];
    const float* bp = (const float*)d_in[8];

    float* out = (float*)d_out;
    float* a_out = out + (size_t)BSZ * MDIM * TDIM * CDIM;   // 24903680

    float* xsum = (float*)d_ws;                                         // 1 MB (2 halves)
    ushort_t* wbf = (ushort_t*)((char*)d_ws + 1048576);                 // 8 MB
    ushort_t* vtb = (ushort_t*)((char*)d_ws + 1048576 + 8388608);       // 47.5 MB

    k_xsum<<<1024, 256, 0, stream>>>(x, xsum);
    k_vproj<<<3040, 256, 0, stream>>>(x, Wv, bv, vtb);
    k_weights<<<256, 256, 0, stream>>>(xsum, Wq, bq, Wk, bk, wbf, a_out);
    k_att<<<768, 256, 0, stream>>>(wbf, vtb, Wp, bp, out);
}

// Round 3
// 153.050 us; speedup vs baseline: 1.1083x; 1.0217x over previous
//
#include <hip/hip_runtime.h>

typedef unsigned short ushort_t;
typedef __bf16 bf16x8 __attribute__((ext_vector_type(8)));
typedef float f32x4 __attribute__((ext_vector_type(4)));

#define DEVI __device__ __forceinline__

constexpr int BSZ = 4;     // batch
constexpr int MDIM = 190;  // axial dim
constexpr int TDIM = 512;  // seq
constexpr int CDIM = 64;   // channels

DEVI ushort_t f2bf(float f) {
    union { float f; unsigned int u; } v; v.f = f;
    unsigned int u = v.u;
    u += 0x7FFFu + ((u >> 16) & 1u);   // round-to-nearest-even
    return (ushort_t)(u >> 16);
}

DEVI void gload16(ushort_t* ldsBase, const ushort_t* g) {
    __builtin_amdgcn_global_load_lds(
        (const __attribute__((address_space(1))) unsigned int*)g,
        (__attribute__((address_space(3))) unsigned int*)ldsBase, 16, 0, 0);
}

// ---------------------------------------------------------------- K1: xsum (2 m-halves for TLP)
__global__ __launch_bounds__(256) void k_xsum(const float* __restrict__ x,
                                              float* __restrict__ xsum) {
    int bid = blockIdx.x;                       // 1024
    int half = bid >> 9;
    int idx = ((bid & 511) << 8) + threadIdx.x; // 0..131071
    int b = idx >> 15;
    const size_t stride = (size_t)TDIM * CDIM;  // 32768
    size_t base = (size_t)b * (MDIM * TDIM * CDIM) + (size_t)(half * 95) * stride + (idx & 32767);
    const float* p = x + base;
    float s[8];
#pragma unroll
    for (int u = 0; u < 8; ++u) s[u] = 0.f;
    for (int m = 0; m + 8 <= 95; m += 8) {      // 11 iters
#pragma unroll
        for (int u = 0; u < 8; ++u) s[u] += p[(size_t)u * stride];
        p += 8 * stride;
    }
#pragma unroll
    for (int u = 0; u < 7; ++u) s[u] += p[(size_t)u * stride];  // 95 = 88+7
    float t0 = (s[0] + s[1]) + (s[2] + s[3]);
    float t1 = (s[4] + s[5]) + (s[6] + s[7]);
    xsum[(half << 17) + idx] = t0 + t1;
}

// ---------------------------------------------------------------- K2: weights (qt/kt + softmax)
__global__ __launch_bounds__(256) void k_weights(const float* __restrict__ xsum,
                                                 const float* __restrict__ Wq,
                                                 const float* __restrict__ bq,
                                                 const float* __restrict__ Wk,
                                                 const float* __restrict__ bk,
                                                 ushort_t* __restrict__ wbf,
                                                 float* __restrict__ a_out) {
    __shared__ __align__(16) float kt[512][20];
    __shared__ __align__(16) float qt[32][20];
    __shared__ __align__(16) float xs[64][68];
    __shared__ __align__(16) float wcol[64][16];
    __shared__ float kbias[16], qbias[16];

    int tid = threadIdx.x;
    int bid = blockIdx.x;        // 256 blocks
    int tcn = bid & 15;          // t-chunk (32 rows)
    int n = (bid >> 4) & 3;
    int b = bid >> 6;
    int t0 = tcn * 32;

    for (int j = tid; j < 1024; j += 256) {
        int c = j >> 4, d = j & 15;
        wcol[c][d] = Wk[c * 64 + n * 16 + d];
    }
    if (tid < 16) kbias[tid] = 190.0f * bk[n * 16 + tid];
    if (tid >= 16 && tid < 32) qbias[tid - 16] = 190.0f * bq[n * 16 + tid - 16];
    __syncthreads();

    for (int ch = 0; ch < 8; ++ch) {
        for (int j = tid; j < 4096; j += 256) {
            int t = j >> 6, c = j & 63;
            size_t ix = ((size_t)(b * 512) + (ch * 64 + t)) * 64 + c;
            xs[t][c] = xsum[ix] + xsum[ix + 131072];
        }
        __syncthreads();
#pragma unroll
        for (int o = 0; o < 4; ++o) {
            int oi = o * 256 + tid;
            int t = oi >> 4, d = oi & 15;
            float s = 0.f;
#pragma unroll
            for (int c = 0; c < 64; ++c) s += xs[t][c] * wcol[c][d];
            kt[ch * 64 + t][d] = s + kbias[d];
        }
        __syncthreads();
    }

    for (int j = tid; j < 1024; j += 256) {
        int c = j >> 4, d = j & 15;
        wcol[c][d] = Wq[c * 64 + n * 16 + d];
    }
    for (int j = tid; j < 2048; j += 256) {
        int t = j >> 6, c = j & 63;
        size_t ix = ((size_t)(b * 512) + (t0 + t)) * 64 + c;
        xs[t][c] = xsum[ix] + xsum[ix + 131072];
    }
    __syncthreads();
#pragma unroll
    for (int o = 0; o < 2; ++o) {
        int oi = o * 256 + tid;
        int t = oi >> 4, d = oi & 15;
        float s = 0.f;
#pragma unroll
        for (int c = 0; c < 64; ++c) s += xs[t][c] * wcol[c][d];
        qt[t][d] = s + qbias[d];
    }
    __syncthreads();

    const float scale = 0.01813692f;  // 1/sqrt(16*190)
    int w = tid >> 6, lane = tid & 63;
    for (int rr = 0; rr < 8; ++rr) {
        int r = w * 8 + rr;
        float qreg[16];
#pragma unroll
        for (int d = 0; d < 16; ++d) qreg[d] = qt[r][d];
        float lv[8];
#pragma unroll
        for (int i = 0; i < 8; ++i) {
            int k = lane + 64 * i;
            const float* kr = &kt[k][0];
            float s = 0.f;
#pragma unroll
            for (int d = 0; d < 16; ++d) s += qreg[d] * kr[d];
            lv[i] = s * scale;
        }
        float mx = lv[0];
#pragma unroll
        for (int i = 1; i < 8; ++i) mx = fmaxf(mx, lv[i]);
#pragma unroll
        for (int off = 32; off >= 1; off >>= 1) mx = fmaxf(mx, __shfl_xor(mx, off));
        float se = 0.f;
#pragma unroll
        for (int i = 0; i < 8; ++i) { lv[i] = __expf(lv[i] - mx); se += lv[i]; }
#pragma unroll
        for (int off = 32; off >= 1; off >>= 1) se += __shfl_xor(se, off);
        float inv = 1.0f / se;

        size_t wbase = ((size_t)((b * 4 + n) * 512 + (t0 + r))) * 512;
        size_t abase = ((size_t)(n * 512 + (t0 + r))) * 512;
#pragma unroll
        for (int i = 0; i < 8; ++i) {
            float wv = lv[i] * inv;
            wbf[wbase + lane + 64 * i] = f2bf(wv);
            if (b == 0) a_out[abase + lane + 64 * i] = wv;
        }
    }
}

// ---------------------------------------------------------------- K3: v = x@Wv, store bf16 transposed vt[b][m][c][t]
__global__ __launch_bounds__(256) void k_vproj(const float* __restrict__ x,
                                               const float* __restrict__ Wv,
                                               const float* __restrict__ bv,
                                               ushort_t* __restrict__ vt) {
    __shared__ __align__(16) ushort_t u0[128 * 72];
    __shared__ __align__(16) ushort_t WvT[64 * 72];

    int tid = threadIdx.x;
    int bid = blockIdx.x;                 // 3040
    int ttile = bid & 3;
    int m = (bid >> 2) % 190;
    int b = bid / (4 * 190);
    int t0 = ttile * 128;

    size_t xbase = ((size_t)(b * 190 + m) * 512 + t0) * 64;
#pragma unroll
    for (int rep = 0; rep < 8; ++rep) {
        int j = rep * 256 + tid;
        int t = j >> 4, c4 = (j & 15) * 4;
        float4 v = *(const float4*)(x + xbase + (size_t)t * 64 + c4);
        ushort4 h;
        h.x = f2bf(v.x); h.y = f2bf(v.y); h.z = f2bf(v.z); h.w = f2bf(v.w);
        *(ushort4*)&u0[t * 72 + c4] = h;
    }
#pragma unroll
    for (int rep = 0; rep < 16; ++rep) {
        int j = rep * 256 + tid;
        int ci = j >> 6, co = j & 63;
        WvT[co * 72 + ci] = f2bf(Wv[j]);
    }
    __syncthreads();

    int w = tid >> 6, lane = tid & 63;
    int la = lane & 15, lb = lane >> 4;
    f32x4 zz = {0.f, 0.f, 0.f, 0.f};
    f32x4 acc[2][4];
#pragma unroll
    for (int q = 0; q < 2; ++q)
#pragma unroll
        for (int cf = 0; cf < 4; ++cf) acc[q][cf] = zz;

#pragma unroll
    for (int ks = 0; ks < 2; ++ks) {
        bf16x8 a0 = *(const bf16x8*)&u0[(32 * w + la) * 72 + ks * 32 + lb * 8];
        bf16x8 a1 = *(const bf16x8*)&u0[(32 * w + 16 + la) * 72 + ks * 32 + lb * 8];
#pragma unroll
        for (int cf = 0; cf < 4; ++cf) {
            bf16x8 bb = *(const bf16x8*)&WvT[(16 * cf + la) * 72 + ks * 32 + lb * 8];
            acc[0][cf] = __builtin_amdgcn_mfma_f32_16x16x32_bf16(a0, bb, acc[0][cf], 0, 0, 0);
            acc[1][cf] = __builtin_amdgcn_mfma_f32_16x16x32_bf16(a1, bb, acc[1][cf], 0, 0, 0);
        }
    }
    __syncthreads();

    float bvv[4];
#pragma unroll
    for (int cf = 0; cf < 4; ++cf) bvv[cf] = bv[16 * cf + la];

#pragma unroll
    for (int q = 0; q < 2; ++q)
#pragma unroll
        for (int cf = 0; cf < 4; ++cf) {
            int t = 32 * w + 16 * q + lb * 4;
            int c = 16 * cf + la;
            ushort4 h;
            h.x = f2bf(acc[q][cf][0] + bvv[cf]);
            h.y = f2bf(acc[q][cf][1] + bvv[cf]);
            h.z = f2bf(acc[q][cf][2] + bvv[cf]);
            h.w = f2bf(acc[q][cf][3] + bvv[cf]);
            *(ushort4*)&u0[c * 136 + t] = h;
        }
    __syncthreads();

    size_t vbase = ((size_t)(b * 190 + m) * 64) * 512 + t0;
#pragma unroll
    for (int rep = 0; rep < 4; ++rep) {
        int j = rep * 256 + tid;
        int c = j >> 4, s = j & 15;
        uint4 vv = *(const uint4*)&u0[c * 136 + s * 8];
        *(uint4*)(vt + vbase + (size_t)c * 512 + s * 8) = vv;
    }
}

// ---------------------------------------------------------------- K4: att, 2-phase ping-pong pipeline
// Phase (kc, np): stage W heads {2np,2np+1} (64 t rows x 32 k) + V cols [np*32, np*32+32) (8 m x 32 c x 32 k)
// buffer = 24KB: W 8KB (128 rows x 64B) + V 16KB (256 rows x 64B). Two buffers ping-pong.
__global__ __launch_bounds__(256, 3) void k_att(const ushort_t* __restrict__ wbf,
                                                const ushort_t* __restrict__ vt,
                                                const float* __restrict__ Wp,
                                                const float* __restrict__ bp,
                                                float* __restrict__ out) {
    __shared__ __align__(16) ushort_t lds[24576];   // 48KB: buf0 @0, buf1 @12288; epilogue attS @0, WpT @18432

    int tid = threadIdx.x;
    int bid0 = blockIdx.x;                    // 768 = 4b * 24mt * 8tt
    int bid = (bid0 & 7) * 96 + (bid0 >> 3);  // XCD-aware bijective swizzle
    int ttile = bid & 7;
    int mt = (bid >> 3) % 24;
    int b = bid / 192;
    int t0 = ttile * 64;

    int w = tid >> 6, lane = tid & 63;
    int la = lane & 15, lb = lane >> 4;

    // ---- per-thread staging constants (source pre-swizzled; LDS dest linear, rule 21)
    // W: 2 units/thread. unit u = ci*64+lane, ci = w*2+cw; row r = u>>2 (nn*64+trel); s = (u&3)^((r>>1)&3)
    unsigned wbase0[2]; int wldso[2];
#pragma unroll
    for (int cw = 0; cw < 2; ++cw) {
        int ci = w * 2 + cw;
        int u = ci * 64 + lane;
        int r = u >> 2;
        int s = (u & 3) ^ ((r >> 1) & 3);
        int nn = r >> 6, trel = r & 63;
        wbase0[cw] = (unsigned)(((b * 4 + nn) * 512 + t0 + trel) * 512 + s * 8);
        wldso[cw] = ci * 512;                    // ushort offset within buffer W region
    }
    // V: 4 units/thread. unit u = cj*64+lane, cj = w*4+cv; row r = u>>2 (mrel*32+crel)
    unsigned vbase0[4]; int vldso[4];
#pragma unroll
    for (int cv = 0; cv < 4; ++cv) {
        int cj = w * 4 + cv;
        int u = cj * 64 + lane;
        int r = u >> 2;
        int s = (u & 3) ^ ((r >> 1) & 3);
        int mrel = r >> 5, crel = r & 31;
        int mg = mt * 8 + mrel; if (mg > 189) mg = 189;
        vbase0[cv] = (unsigned)(((b * 190 + mg) * 64 + crel) * 512 + s * 8);
        vldso[cv] = 4096 + cj * 512;
    }

    // ---- per-thread LDS read offsets (ushort units), swizzled
    int offA[2][4], offB[2][2];
#pragma unroll
    for (int nn = 0; nn < 2; ++nn) {
#pragma unroll
        for (int q = 0; q < 4; ++q) {
            int row = nn * 64 + 16 * q + la;
            offA[nn][q] = row * 32 + (lb ^ ((row >> 1) & 3)) * 8;
        }
#pragma unroll
        for (int pp = 0; pp < 2; ++pp) {
            int row = (w * 2 + pp) * 32 + nn * 16 + la;
            offB[pp][nn] = 4096 + row * 32 + (lb ^ ((row >> 1) & 3)) * 8;
        }
    }

    f32x4 zz = {0.f, 0.f, 0.f, 0.f};
    f32x4 acc[2][4][4];
#pragma unroll
    for (int p = 0; p < 2; ++p)
#pragma unroll
        for (int n = 0; n < 4; ++n)
#pragma unroll
            for (int q = 0; q < 4; ++q) acc[p][n][q] = zz;

#define STAGE(KC, NP, PAR) do {                                                   \
    int phW = (NP) * 524288 + (KC) * 32;                                          \
    int phV = (NP) * 16384 + (KC) * 32;                                           \
    ushort_t* bufb = lds + (PAR) * 12288;                                         \
    gload16(bufb + wldso[0], wbf + wbase0[0] + phW);                              \
    gload16(bufb + wldso[1], wbf + wbase0[1] + phW);                              \
    gload16(bufb + vldso[0], vt + vbase0[0] + phV);                               \
    gload16(bufb + vldso[1], vt + vbase0[1] + phV);                               \
    gload16(bufb + vldso[2], vt + vbase0[2] + phV);                               \
    gload16(bufb + vldso[3], vt + vbase0[3] + phV);                               \
} while (0)

#define COMPUTE(NP, PAR) do {                                                     \
    const ushort_t* bufc = lds + (PAR) * 12288;                                   \
    __builtin_amdgcn_s_setprio(1);                                                \
    _Pragma("unroll")                                                             \
    for (int nn = 0; nn < 2; ++nn) {                                              \
        bf16x8 bb0 = *(const bf16x8*)(bufc + offB[0][nn]);                        \
        bf16x8 bb1 = *(const bf16x8*)(bufc + offB[1][nn]);                        \
        _Pragma("unroll")                                                         \
        for (int q = 0; q < 4; ++q) {                                             \
            bf16x8 aa = *(const bf16x8*)(bufc + offA[nn][q]);                     \
            acc[0][(NP)*2+nn][q] = __builtin_amdgcn_mfma_f32_16x16x32_bf16(aa, bb0, acc[0][(NP)*2+nn][q], 0, 0, 0); \
            acc[1][(NP)*2+nn][q] = __builtin_amdgcn_mfma_f32_16x16x32_bf16(aa, bb1, acc[1][(NP)*2+nn][q], 0, 0, 0); \
        }                                                                         \
    }                                                                             \
    __builtin_amdgcn_s_setprio(0);                                                \
} while (0)

    // prologue
    STAGE(0, 0, 0);
    __syncthreads();

    for (int kc = 0; kc < 16; ++kc) {
        // phase 2kc (np=0, par=0): stage next phase (kc, np=1) into buf1
        STAGE(kc, 1, 1);
        COMPUTE(0, 0);
        __syncthreads();
        // phase 2kc+1 (np=1, par=1): stage (kc+1, np=0) into buf0
        if (kc < 15) STAGE(kc + 1, 0, 0);
        COMPUTE(1, 1);
        __syncthreads();
    }
#undef STAGE
#undef COMPUTE

    // ---- epilogue: WpT into high region, att -> LDS (two passes), GEMM2
#pragma unroll
    for (int rep = 0; rep < 16; ++rep) {
        int j = rep * 256 + tid;
        int ci2 = j >> 6, co = j & 63;
        lds[18432 + co * 72 + ci2] = f2bf(Wp[j]);
    }
    float bpv[4];
#pragma unroll
    for (int cf = 0; cf < 4; ++cf) bpv[cf] = bp[16 * cf + la];

    for (int p = 0; p < 2; ++p) {
        int m = mt * 8 + w * 2 + p;
#pragma unroll
        for (int n = 0; n < 4; ++n)
#pragma unroll
            for (int q = 0; q < 4; ++q)
#pragma unroll
                for (int r = 0; r < 4; ++r)
                    lds[(w * 64 + 16 * q + lb * 4 + r) * 72 + 16 * n + la] = f2bf(acc[p][n][q][r]);
        __syncthreads();

        f32x4 acc2[4][4];
#pragma unroll
        for (int q = 0; q < 4; ++q)
#pragma unroll
            for (int cf = 0; cf < 4; ++cf) acc2[q][cf] = zz;
#pragma unroll
        for (int ks = 0; ks < 2; ++ks) {
            bf16x8 wb[4];
#pragma unroll
            for (int cf = 0; cf < 4; ++cf)
                wb[cf] = *(const bf16x8*)(lds + 18432 + (16 * cf + la) * 72 + ks * 32 + lb * 8);
#pragma unroll
            for (int q = 0; q < 4; ++q) {
                bf16x8 aa = *(const bf16x8*)(lds + (w * 64 + 16 * q + la) * 72 + ks * 32 + lb * 8);
#pragma unroll
                for (int cf = 0; cf < 4; ++cf)
                    acc2[q][cf] = __builtin_amdgcn_mfma_f32_16x16x32_bf16(aa, wb[cf], acc2[q][cf], 0, 0, 0);
            }
        }
        if (m < 190) {
            size_t obase = ((size_t)(b * 190 + m) * 512 + t0) * 64;
#pragma unroll
            for (int q = 0; q < 4; ++q)
#pragma unroll
                for (int r = 0; r < 4; ++r) {
                    int t = 16 * q + lb * 4 + r;
#pragma unroll
                    for (int cf = 0; cf < 4; ++cf)
                        out[obase + (size_t)t * 64 + 16 * cf + la] = acc2[q][cf][r] + bpv[cf];
                }
        }
        __syncthreads();
    }
}

// ----------------------------------------------------------------
extern "C" void kernel_launch(void* const* d_in, const int* in_sizes, int n_in,
                              void* d_out, int out_size, void* d_ws, size_t ws_size,
                              hipStream_t stream) {
    const float* x  = (const float*)d_in[0];
    const float* Wq = (const float*)d_in[1];
    const float* bq = (const float*)d_in[2];
    const float* Wk = (const float*)d_in[3];
    const float* bk = (const float*)d_in[4];
    const float* Wv = (const float*)d_in[5];
    const float* bv = (const float*)d_in[6];
    const float* Wp = (const float*)d_in[7];
    const float* bp = (const float*)d_in[8];

    float* out = (float*)d_out;
    float* a_out = out + (size_t)BSZ * MDIM * TDIM * CDIM;   // 24903680

    float* xsum = (float*)d_ws;                                         // 1 MB (2 halves)
    ushort_t* wbf = (ushort_t*)((char*)d_ws + 1048576);                 // 8 MB
    ushort_t* vtb = (ushort_t*)((char*)d_ws + 1048576 + 8388608);       // 47.5 MB

    k_xsum<<<1024, 256, 0, stream>>>(x, xsum);
    k_vproj<<<3040, 256, 0, stream>>>(x, Wv, bv, vtb);
    k_weights<<<256, 256, 0, stream>>>(xsum, Wq, bq, Wk, bk, wbf, a_out);
    k_att<<<768, 256, 0, stream>>>(wbf, vtb, Wp, bp, out);
}

// Round 4
// 143.909 us; speedup vs baseline: 1.1787x; 1.0635x over previous
//
#include <hip/hip_runtime.h>

typedef unsigned short ushort_t;
typedef __bf16 bf16x8 __attribute__((ext_vector_type(8)));
typedef float f32x4 __attribute__((ext_vector_type(4)));

#define DEVI __device__ __forceinline__

constexpr int BSZ = 4;     // batch
constexpr int MDIM = 190;  // axial dim
constexpr int TDIM = 512;  // seq
constexpr int CDIM = 64;   // channels

DEVI ushort_t f2bf(float f) {
    union { float f; unsigned int u; } v; v.f = f;
    unsigned int u = v.u;
    u += 0x7FFFu + ((u >> 16) & 1u);   // round-to-nearest-even
    return (ushort_t)(u >> 16);
}

DEVI void gload16(ushort_t* ldsBase, const ushort_t* g) {
    __builtin_amdgcn_global_load_lds(
        (const __attribute__((address_space(1))) unsigned int*)g,
        (__attribute__((address_space(3))) unsigned int*)ldsBase, 16, 0, 0);
}

// ---------------------------------------------------------------- K1: fused v-projection + xsum partials
// block = (b, tt of 64 t, mg of 12 m). Reads x once; writes vt bf16 transposed + xsum partial (part=mg).
__global__ __launch_bounds__(256, 4) void k_vproj(const float* __restrict__ x,
                                                  const float* __restrict__ Wv,
                                                  const float* __restrict__ bv,
                                                  ushort_t* __restrict__ vt,
                                                  float* __restrict__ xsp) {
    __shared__ __align__(16) ushort_t xbf[64 * 72];
    __shared__ __align__(16) ushort_t WvT[64 * 72];
    __shared__ __align__(16) ushort_t vst[64 * 72];

    int tid = threadIdx.x;
    int bid = blockIdx.x;            // 512 = 4b * 8tt * 16mg
    int mg = bid & 15;
    int tt = (bid >> 4) & 7;
    int b = bid >> 7;
    int t0 = tt * 64;
    int mbase = mg * 12;
    int cnt = (mbase + 12 <= MDIM) ? 12 : (MDIM - mbase);   // 12 or 10

    int w = tid >> 6, lane = tid & 63;
    int la = lane & 15, lb = lane >> 4;
    int r = tid >> 2, seg = tid & 3;

#pragma unroll
    for (int rep = 0; rep < 16; ++rep) {
        int j = rep * 256 + tid;
        int ci = j >> 6, co = j & 63;
        WvT[co * 72 + ci] = f2bf(Wv[j]);
    }
    float bvv[4];
#pragma unroll
    for (int cf = 0; cf < 4; ++cf) bvv[cf] = bv[16 * cf + la];

    float xacc[16];
#pragma unroll
    for (int u = 0; u < 16; ++u) xacc[u] = 0.f;

    const size_t mstride = (size_t)TDIM * CDIM;  // 32768
    size_t xaddr = ((size_t)(b * MDIM + mbase) * TDIM + t0 + r) * CDIM + seg * 16;

    float4 xv[4];
#pragma unroll
    for (int u = 0; u < 4; ++u) xv[u] = *(const float4*)(x + xaddr + u * 4);

    f32x4 zz = {0.f, 0.f, 0.f, 0.f};

    for (int i = 0; i < cnt; ++i) {
        // A: accumulate xsum (fp32) + convert + ds_write xbf
#pragma unroll
        for (int u = 0; u < 4; ++u) {
            xacc[u * 4 + 0] += xv[u].x;
            xacc[u * 4 + 1] += xv[u].y;
            xacc[u * 4 + 2] += xv[u].z;
            xacc[u * 4 + 3] += xv[u].w;
            ushort4 h;
            h.x = f2bf(xv[u].x); h.y = f2bf(xv[u].y);
            h.z = f2bf(xv[u].z); h.w = f2bf(xv[u].w);
            *(ushort4*)&xbf[r * 72 + seg * 16 + u * 4] = h;
        }
        __syncthreads();

        // C: prefetch next m's x; MFMA; write frags to vst
        int inext = (i + 1 < cnt) ? (i + 1) : i;
        size_t xaddr2 = xaddr + (size_t)(inext - i) * mstride;
        float4 xv2[4];
#pragma unroll
        for (int u = 0; u < 4; ++u) xv2[u] = *(const float4*)(x + xaddr2 + u * 4);

        f32x4 acc2[4];
#pragma unroll
        for (int cf = 0; cf < 4; ++cf) acc2[cf] = zz;
#pragma unroll
        for (int ks = 0; ks < 2; ++ks) {
            bf16x8 aa = *(const bf16x8*)&xbf[(w * 16 + la) * 72 + ks * 32 + lb * 8];
#pragma unroll
            for (int cf = 0; cf < 4; ++cf) {
                bf16x8 bb = *(const bf16x8*)&WvT[(16 * cf + la) * 72 + ks * 32 + lb * 8];
                acc2[cf] = __builtin_amdgcn_mfma_f32_16x16x32_bf16(aa, bb, acc2[cf], 0, 0, 0);
            }
        }
#pragma unroll
        for (int cf = 0; cf < 4; ++cf) {
            ushort4 h;
            h.x = f2bf(acc2[cf][0] + bvv[cf]);
            h.y = f2bf(acc2[cf][1] + bvv[cf]);
            h.z = f2bf(acc2[cf][2] + bvv[cf]);
            h.w = f2bf(acc2[cf][3] + bvv[cf]);
            *(ushort4*)&vst[(16 * cf + la) * 72 + w * 16 + lb * 4] = h;
        }
        __syncthreads();

        // D: coalesced global write of vt[b][m][c][t0..t0+63]
        int m = mbase + i;
        size_t vbase = ((size_t)(b * MDIM + m) * CDIM + r) * TDIM + t0 + seg * 16;
        *(uint4*)(vt + vbase) = *(const uint4*)&vst[r * 72 + seg * 16];
        *(uint4*)(vt + vbase + 8) = *(const uint4*)&vst[r * 72 + seg * 16 + 8];

#pragma unroll
        for (int u = 0; u < 4; ++u) xv[u] = xv2[u];
        xaddr = xaddr2;
    }

    // write xsum partial: xsp[mg][b][t][c]
    size_t sbase = ((size_t)(mg * 4 + b) * TDIM + t0 + r) * CDIM + seg * 16;
#pragma unroll
    for (int u = 0; u < 4; ++u) {
        float4 o;
        o.x = xacc[u * 4 + 0]; o.y = xacc[u * 4 + 1];
        o.z = xacc[u * 4 + 2]; o.w = xacc[u * 4 + 3];
        *(float4*)(xsp + sbase + u * 4) = o;
    }
}

// ---------------------------------------------------------------- K1b: reduce 16 partials -> xsum
__global__ __launch_bounds__(256) void k_xsum2(const float* __restrict__ xsp,
                                               float* __restrict__ xsum) {
    int idx = blockIdx.x * 256 + threadIdx.x;   // 131072
    float s = 0.f;
#pragma unroll
    for (int p = 0; p < 16; ++p) s += xsp[(size_t)p * 131072 + idx];
    xsum[idx] = s;
}

// ---------------------------------------------------------------- K2: weights (qt/kt + softmax)
__global__ __launch_bounds__(256) void k_weights(const float* __restrict__ xsum,
                                                 const float* __restrict__ Wq,
                                                 const float* __restrict__ bq,
                                                 const float* __restrict__ Wk,
                                                 const float* __restrict__ bk,
                                                 ushort_t* __restrict__ wbf,
                                                 float* __restrict__ a_out) {
    __shared__ __align__(16) float kt[512][20];
    __shared__ __align__(16) float qt[32][20];
    __shared__ __align__(16) float xs[64][68];
    __shared__ __align__(16) float wcol[64][16];
    __shared__ float kbias[16], qbias[16];

    int tid = threadIdx.x;
    int bid = blockIdx.x;        // 256 blocks
    int tcn = bid & 15;          // t-chunk (32 rows)
    int n = (bid >> 4) & 3;
    int b = bid >> 6;
    int t0 = tcn * 32;

    for (int j = tid; j < 1024; j += 256) {
        int c = j >> 4, d = j & 15;
        wcol[c][d] = Wk[c * 64 + n * 16 + d];
    }
    if (tid < 16) kbias[tid] = 190.0f * bk[n * 16 + tid];
    if (tid >= 16 && tid < 32) qbias[tid - 16] = 190.0f * bq[n * 16 + tid - 16];
    __syncthreads();

    for (int ch = 0; ch < 8; ++ch) {
        for (int j = tid; j < 4096; j += 256) {
            int t = j >> 6, c = j & 63;
            xs[t][c] = xsum[((size_t)(b * 512) + (ch * 64 + t)) * 64 + c];
        }
        __syncthreads();
#pragma unroll
        for (int o = 0; o < 4; ++o) {
            int oi = o * 256 + tid;
            int t = oi >> 4, d = oi & 15;
            float s = 0.f;
#pragma unroll
            for (int c = 0; c < 64; ++c) s += xs[t][c] * wcol[c][d];
            kt[ch * 64 + t][d] = s + kbias[d];
        }
        __syncthreads();
    }

    for (int j = tid; j < 1024; j += 256) {
        int c = j >> 4, d = j & 15;
        wcol[c][d] = Wq[c * 64 + n * 16 + d];
    }
    for (int j = tid; j < 2048; j += 256) {
        int t = j >> 6, c = j & 63;
        xs[t][c] = xsum[((size_t)(b * 512) + (t0 + t)) * 64 + c];
    }
    __syncthreads();
#pragma unroll
    for (int o = 0; o < 2; ++o) {
        int oi = o * 256 + tid;
        int t = oi >> 4, d = oi & 15;
        float s = 0.f;
#pragma unroll
        for (int c = 0; c < 64; ++c) s += xs[t][c] * wcol[c][d];
        qt[t][d] = s + qbias[d];
    }
    __syncthreads();

    const float scale = 0.01813692f;  // 1/sqrt(16*190)
    int w = tid >> 6, lane = tid & 63;
    for (int rr = 0; rr < 8; ++rr) {
        int r = w * 8 + rr;
        float qreg[16];
#pragma unroll
        for (int d = 0; d < 16; ++d) qreg[d] = qt[r][d];
        float lv[8];
#pragma unroll
        for (int i = 0; i < 8; ++i) {
            int k = lane + 64 * i;
            const float* kr = &kt[k][0];
            float s = 0.f;
#pragma unroll
            for (int d = 0; d < 16; ++d) s += qreg[d] * kr[d];
            lv[i] = s * scale;
        }
        float mx = lv[0];
#pragma unroll
        for (int i = 1; i < 8; ++i) mx = fmaxf(mx, lv[i]);
#pragma unroll
        for (int off = 32; off >= 1; off >>= 1) mx = fmaxf(mx, __shfl_xor(mx, off));
        float se = 0.f;
#pragma unroll
        for (int i = 0; i < 8; ++i) { lv[i] = __expf(lv[i] - mx); se += lv[i]; }
#pragma unroll
        for (int off = 32; off >= 1; off >>= 1) se += __shfl_xor(se, off);
        float inv = 1.0f / se;

        size_t wbase = ((size_t)((b * 4 + n) * 512 + (t0 + r))) * 512;
        size_t abase = ((size_t)(n * 512 + (t0 + r))) * 512;
#pragma unroll
        for (int i = 0; i < 8; ++i) {
            float wv = lv[i] * inv;
            wbf[wbase + lane + 64 * i] = f2bf(wv);
            if (b == 0) a_out[abase + lane + 64 * i] = wv;
        }
    }
}

// ---------------------------------------------------------------- K4: att, 2-buffer pipeline w/ COUNTED vmcnt
__global__ __launch_bounds__(256, 3) void k_att(const ushort_t* __restrict__ wbf,
                                                const ushort_t* __restrict__ vt,
                                                const float* __restrict__ Wp,
                                                const float* __restrict__ bp,
                                                float* __restrict__ out) {
    __shared__ __align__(16) ushort_t lds[24576];   // 48KB: buf0 @0, buf1 @12288; epilogue attS @0, WpT @18432

    int tid = threadIdx.x;
    int bid0 = blockIdx.x;                    // 768 = 4b * 24mt * 8tt
    int bid = (bid0 & 7) * 96 + (bid0 >> 3);  // XCD-aware bijective swizzle
    int ttile = bid & 7;
    int mt = (bid >> 3) % 24;
    int b = bid / 192;
    int t0 = ttile * 64;

    int w = tid >> 6, lane = tid & 63;
    int la = lane & 15, lb = lane >> 4;

    // staging constants (source pre-swizzled; LDS dest linear, rule 21)
    unsigned wbase0[2]; int wldso[2];
#pragma unroll
    for (int cw = 0; cw < 2; ++cw) {
        int ci = w * 2 + cw;
        int u = ci * 64 + lane;
        int r = u >> 2;
        int s = (u & 3) ^ ((r >> 1) & 3);
        int nn = r >> 6, trel = r & 63;
        wbase0[cw] = (unsigned)(((b * 4 + nn) * 512 + t0 + trel) * 512 + s * 8);
        wldso[cw] = ci * 512;
    }
    unsigned vbase0[4]; int vldso[4];
#pragma unroll
    for (int cv = 0; cv < 4; ++cv) {
        int cj = w * 4 + cv;
        int u = cj * 64 + lane;
        int r = u >> 2;
        int s = (u & 3) ^ ((r >> 1) & 3);
        int mrel = r >> 5, crel = r & 31;
        int mg = mt * 8 + mrel; if (mg > 189) mg = 189;
        vbase0[cv] = (unsigned)(((b * 190 + mg) * 64 + crel) * 512 + s * 8);
        vldso[cv] = 4096 + cj * 512;
    }

    int offA[2][4], offB[2][2];
#pragma unroll
    for (int nn = 0; nn < 2; ++nn) {
#pragma unroll
        for (int q = 0; q < 4; ++q) {
            int row = nn * 64 + 16 * q + la;
            offA[nn][q] = row * 32 + (lb ^ ((row >> 1) & 3)) * 8;
        }
#pragma unroll
        for (int pp = 0; pp < 2; ++pp) {
            int row = (w * 2 + pp) * 32 + nn * 16 + la;
            offB[pp][nn] = 4096 + row * 32 + (lb ^ ((row >> 1) & 3)) * 8;
        }
    }

    f32x4 zz = {0.f, 0.f, 0.f, 0.f};
    f32x4 acc[2][4][4];
#pragma unroll
    for (int p = 0; p < 2; ++p)
#pragma unroll
        for (int n = 0; n < 4; ++n)
#pragma unroll
            for (int q = 0; q < 4; ++q) acc[p][n][q] = zz;

#define STAGE(KC, NP, PAR) do {                                                   \
    int phW = (NP) * 524288 + (KC) * 32;                                          \
    int phV = (NP) * 16384 + (KC) * 32;                                           \
    ushort_t* bufb = lds + (PAR) * 12288;                                         \
    gload16(bufb + wldso[0], wbf + wbase0[0] + phW);                              \
    gload16(bufb + wldso[1], wbf + wbase0[1] + phW);                              \
    gload16(bufb + vldso[0], vt + vbase0[0] + phV);                               \
    gload16(bufb + vldso[1], vt + vbase0[1] + phV);                               \
    gload16(bufb + vldso[2], vt + vbase0[2] + phV);                               \
    gload16(bufb + vldso[3], vt + vbase0[3] + phV);                               \
} while (0)

#define COMPUTE(NP, PAR) do {                                                     \
    const ushort_t* bufc = lds + (PAR) * 12288;                                   \
    __builtin_amdgcn_s_setprio(1);                                                \
    _Pragma("unroll")                                                             \
    for (int nn = 0; nn < 2; ++nn) {                                              \
        bf16x8 bb0 = *(const bf16x8*)(bufc + offB[0][nn]);                        \
        bf16x8 bb1 = *(const bf16x8*)(bufc + offB[1][nn]);                        \
        _Pragma("unroll")                                                         \
        for (int q = 0; q < 4; ++q) {                                             \
            bf16x8 aa = *(const bf16x8*)(bufc + offA[nn][q]);                     \
            acc[0][(NP)*2+nn][q] = __builtin_amdgcn_mfma_f32_16x16x32_bf16(aa, bb0, acc[0][(NP)*2+nn][q], 0, 0, 0); \
            acc[1][(NP)*2+nn][q] = __builtin_amdgcn_mfma_f32_16x16x32_bf16(aa, bb1, acc[1][(NP)*2+nn][q], 0, 0, 0); \
        }                                                                         \
    }                                                                             \
    __builtin_amdgcn_s_setprio(0);                                                \
} while (0)

#define VMW6 asm volatile("s_waitcnt vmcnt(6)" ::: "memory")
#define VMW0 asm volatile("s_waitcnt vmcnt(0)" ::: "memory")

    // prologue: phases 0,1 in flight (12 outstanding)
    STAGE(0, 0, 0);
    STAGE(0, 1, 1);

    for (int kc = 0; kc < 15; ++kc) {
        VMW6;                               // phase 2kc's 6 loads done (next 6 stay in flight)
        __builtin_amdgcn_s_barrier();
        COMPUTE(0, 0);
        __builtin_amdgcn_s_barrier();       // all waves done reading buf0
        STAGE(kc + 1, 0, 0);                // phase 2kc+2 -> buf0
        VMW6;
        __builtin_amdgcn_s_barrier();
        COMPUTE(1, 1);
        __builtin_amdgcn_s_barrier();
        STAGE(kc + 1, 1, 1);                // phase 2kc+3 -> buf1
    }
    // tail: phases 30, 31
    VMW6;
    __builtin_amdgcn_s_barrier();
    COMPUTE(0, 0);
    VMW0;
    __builtin_amdgcn_s_barrier();
    COMPUTE(1, 1);
    __syncthreads();                        // full drain before epilogue reuses LDS
#undef STAGE
#undef COMPUTE
#undef VMW6
#undef VMW0

    // ---- epilogue: WpT into high region, att -> LDS (two passes), GEMM2
#pragma unroll
    for (int rep = 0; rep < 16; ++rep) {
        int j = rep * 256 + tid;
        int ci2 = j >> 6, co = j & 63;
        lds[18432 + co * 72 + ci2] = f2bf(Wp[j]);
    }
    float bpv[4];
#pragma unroll
    for (int cf = 0; cf < 4; ++cf) bpv[cf] = bp[16 * cf + la];

    for (int p = 0; p < 2; ++p) {
        int m = mt * 8 + w * 2 + p;
#pragma unroll
        for (int n = 0; n < 4; ++n)
#pragma unroll
            for (int q = 0; q < 4; ++q)
#pragma unroll
                for (int r = 0; r < 4; ++r)
                    lds[(w * 64 + 16 * q + lb * 4 + r) * 72 + 16 * n + la] = f2bf(acc[p][n][q][r]);
        __syncthreads();

        f32x4 acc2[4][4];
#pragma unroll
        for (int q = 0; q < 4; ++q)
#pragma unroll
            for (int cf = 0; cf < 4; ++cf) acc2[q][cf] = zz;
#pragma unroll
        for (int ks = 0; ks < 2; ++ks) {
            bf16x8 wb[4];
#pragma unroll
            for (int cf = 0; cf < 4; ++cf)
                wb[cf] = *(const bf16x8*)(lds + 18432 + (16 * cf + la) * 72 + ks * 32 + lb * 8);
#pragma unroll
            for (int q = 0; q < 4; ++q) {
                bf16x8 aa = *(const bf16x8*)(lds + (w * 64 + 16 * q + la) * 72 + ks * 32 + lb * 8);
#pragma unroll
                for (int cf = 0; cf < 4; ++cf)
                    acc2[q][cf] = __builtin_amdgcn_mfma_f32_16x16x32_bf16(aa, wb[cf], acc2[q][cf], 0, 0, 0);
            }
        }
        if (m < 190) {
            size_t obase = ((size_t)(b * 190 + m) * 512 + t0) * 64;
#pragma unroll
            for (int q = 0; q < 4; ++q)
#pragma unroll
                for (int r = 0; r < 4; ++r) {
                    int t = 16 * q + lb * 4 + r;
#pragma unroll
                    for (int cf = 0; cf < 4; ++cf)
                        out[obase + (size_t)t * 64 + 16 * cf + la] = acc2[q][cf][r] + bpv[cf];
                }
        }
        __syncthreads();
    }
}

// ----------------------------------------------------------------
extern "C" void kernel_launch(void* const* d_in, const int* in_sizes, int n_in,
                              void* d_out, int out_size, void* d_ws, size_t ws_size,
                              hipStream_t stream) {
    const float* x  = (const float*)d_in[0];
    const float* Wq = (const float*)d_in[1];
    const float* bq = (const float*)d_in[2];
    const float* Wk = (const float*)d_in[3];
    const float* bk = (const float*)d_in[4];
    const float* Wv = (const float*)d_in[5];
    const float* bv = (const float*)d_in[6];
    const float* Wp = (const float*)d_in[7];
    const float* bp = (const float*)d_in[8];

    float* out = (float*)d_out;
    float* a_out = out + (size_t)BSZ * MDIM * TDIM * CDIM;   // 24903680

    // xsum partials live in the out region (8 MB = 2M floats << 24.9M), fully
    // overwritten later by k_att -> deterministic.
    float* xsp = out;

    float* xsum = (float*)d_ws;                                         // 512 KB
    ushort_t* wbf = (ushort_t*)((char*)d_ws + 524288);                  // 8 MB
    ushort_t* vtb = (ushort_t*)((char*)d_ws + 524288 + 8388608);        // 47.5 MB

    k_vproj<<<512, 256, 0, stream>>>(x, Wv, bv, vtb, xsp);
    k_xsum2<<<512, 256, 0, stream>>>(xsp, xsum);
    k_weights<<<256, 256, 0, stream>>>(xsum, Wq, bq, Wk, bk, wbf, a_out);
    k_att<<<768, 256, 0, stream>>>(wbf, vtb, Wp, bp, out);
}